// Round 16
// baseline (103.606 us; speedup 1.0000x reference)
//
#include <hip/hip_runtime.h>
#include <hip/hip_fp16.h>

// DCNv2 R16: 2-deep gather pipeline (G(n+2) in flight) + setprio(1) on MFMA.
//   k_fused fully unrolled over 9 taps; two dedicated ld reg sets (ldA/ldB)
//   alternate so every blend consumes loads issued TWO barriers earlier.
//   PRM param strips 3-deep. Raw s_barrier with lgkmcnt-only drain (vmem
//   stays in flight). k_transpose/k_prep/k_offconv(fused params) = R15.

typedef unsigned int u32;
typedef __attribute__((ext_vector_type(8))) _Float16 f16x8;
typedef __attribute__((ext_vector_type(4))) float f32x4;

union U16 { uint4 u; f16x8 h; };
union H2U { __half2 h2; u32 u; };

static __device__ __forceinline__ u32 pkh(float a, float b) {
    H2U c; c.h2 = __float22half2_rn(make_float2(a, b)); return c.u;
}
static __device__ __forceinline__ u32 pkw(float w) {
    __half h = __float2half_rn(w);
    H2U c; c.h2 = __half2(h, h); return c.u;
}
static __device__ __forceinline__ u32 hfma2u(u32 a, u32 w, u32 acc) {
    H2U x, y, z; x.u = a; y.u = w; z.u = acc;
    z.h2 = __hfma2(x.h2, y.h2, z.h2); return z.u;
}
static __device__ __forceinline__ u32 hmul2u(u32 a, u32 w) {
    H2U x, y; x.u = a; y.u = w;
    y.h2 = __hmul2(x.h2, y.h2); return y.u;
}

#define B_   16
#define HW_  4096
#define CU_  64          // 128 ch = 64 fp16-pair words

// ---------------- kernel 1: NCHW f32 -> NHWC fp16 ----------------
__global__ __launch_bounds__(256) void k_transpose(const float* __restrict__ x,
                                                   u32* __restrict__ xtu) {
    __shared__ float tile[32][129];
    int blk = blockIdx.x, t = threadIdx.x;
    int b = blk >> 7, hw0 = (blk & 127) << 5;
    int hwl = t & 31, cg = t >> 5;
    const float* src = x + (size_t)b * 128 * HW_ + hw0 + hwl;
#pragma unroll
    for (int i = 0; i < 16; ++i) { int c = cg + (i << 3); tile[hwl][c] = src[(size_t)c * HW_]; }
    __syncthreads();
    u32* dst = xtu + ((size_t)b * HW_ + hw0) * CU_;
    int u = t & 63, hq = t >> 6;
#pragma unroll
    for (int j = 0; j < 8; ++j) {
        int hw = (hq << 3) + j;
        dst[(size_t)hw * CU_ + u] = pkh(tile[hw][2 * u], tile[hw][2 * u + 1]);
    }
}

// ---------------- kernel 2: weight prep ----------------
__global__ __launch_bounds__(256) void k_prep(const float* __restrict__ weight,
                                              const float* __restrict__ off_w,
                                              uint4* __restrict__ wtv,
                                              u32* __restrict__ woffu) {
    int idx = blockIdx.x * 256 + threadIdx.x;
    if (idx < 18432) {
        int l = idx & 63, og = (idx >> 6) & 7, ks = (idx >> 9) & 3, n = idx >> 11;
        int o = og * 16 + (l & 15);
        int c0 = ks * 32 + (l >> 4) * 8;
        u32 r[4];
#pragma unroll
        for (int q = 0; q < 4; ++q) {
            int c = c0 + 2 * q;
            r[q] = pkh(weight[((size_t)(o * 128 + c)) * 9 + n],
                       weight[((size_t)(o * 128 + c + 1)) * 9 + n]);
        }
        wtv[idx] = make_uint4(r[0], r[1], r[2], r[3]);
    } else {
        int k = idx - 18432;
        int o = k / 576, r = k % 576;
        int tap = r / 64, cu = r % 64, c = cu * 2;
        u32 v = 0u;
        if (o < 27) {
            float a = off_w[((size_t)(o * 128 + c)) * 9 + tap];
            float b = off_w[((size_t)(o * 128 + c + 1)) * 9 + tap];
            v = pkh(a, b);
        }
        woffu[k] = v;
    }
}

// ---------------- kernel 3: offset/mask conv + params (fused) ----------------
__global__ __launch_bounds__(256) void k_offconv(const u32* __restrict__ xtu,
                                                 const u32* __restrict__ woffu,
                                                 const float* __restrict__ off_b,
                                                 u32* __restrict__ params) {
    __shared__ __align__(16) u32 S[3][64][64];
    __shared__ float OFF[27][65];
    int blk = ((blockIdx.x & 7) << 7) + (blockIdx.x >> 3);   // XCD-chunked
    int t = threadIdx.x;
    int b = blk >> 6, ho = blk & 63;
    const u32* xb = xtu + (size_t)b * HW_ * CU_;
    const uint4 z4 = {0u, 0u, 0u, 0u};
#pragma unroll
    for (int i = 0; i < 12; ++i) {
        int li = t + (i << 8);
        int r = li >> 10, rem = li & 1023;
        int px = rem >> 4, ch = rem & 15;
        int yy = ho + r - 1;
        uint4 v = ((unsigned)yy < 64u) ? *(const uint4*)(xb + ((yy << 6) + px) * CU_ + (ch << 2)) : z4;
        *(uint4*)&S[r][px][(ch ^ (px & 7)) << 2] = v;
    }
    __syncthreads();
    int lane = t & 63, w = t >> 6, l15 = lane & 15, lhi = lane >> 4;
    int ob = w >> 1, pb0 = (w & 1) << 1;
    f32x4 acc[2];
    acc[0] = (f32x4){0.f, 0.f, 0.f, 0.f};
    acc[1] = (f32x4){0.f, 0.f, 0.f, 0.f};
#pragma unroll 1
    for (int tap = 0; tap < 9; ++tap) {
        int ky = tap / 3, kx = tap % 3;
        int yy = ho + ky - 1;
        if ((unsigned)yy >= 64u) continue;
        U16 af[4];
#pragma unroll
        for (int ks = 0; ks < 4; ++ks)
            af[ks].u = *(const uint4*)(woffu + (size_t)(ob * 16 + l15) * 576
                                       + tap * 64 + ks * 16 + lhi * 4);
#pragma unroll
        for (int pp = 0; pp < 2; ++pp) {
            int pr = ((pb0 + pp) << 4) + l15;
            int pxs = pr + kx - 1;
            bool v = (unsigned)pxs < 64u;
            int pxc = v ? pxs : 0;
#pragma unroll
            for (int ks = 0; ks < 4; ++ks) {
                U16 sf;
                sf.u = v ? *(const uint4*)&S[ky][pxc][((ks * 4 + lhi) ^ (pxc & 7)) << 2] : z4;
                acc[pp] = __builtin_amdgcn_mfma_f32_16x16x32_f16(af[ks].h, sf.h, acc[pp], 0, 0, 0);
            }
        }
    }
    // --- epilogue A: offsets/mask -> OFF LDS ---
#pragma unroll
    for (int pp = 0; pp < 2; ++pp)
#pragma unroll
        for (int r = 0; r < 4; ++r) {
            int o = ob * 16 + lhi * 4 + r;
            if (o < 27) {
                float s = acc[pp][r] + off_b[o];
                if (o >= 18) s = 1.f / (1.f + __expf(-s));
                OFF[o][((pb0 + pp) << 4) + l15] = s;
            }
        }
    __syncthreads();
    // --- epilogue B: params for this (b,ho): 9 taps x 64 px ---
    u32* pbase = params + ((size_t)((b << 6) + ho) * 9) * 512;
#pragma unroll 1
    for (int it = 0; it < 3; ++it) {
        int item = it * 256 + t;
        if (item < 576) {
            int tap = item >> 6, px = item & 63;
            float dy = OFF[2 * tap][px];
            float dx = OFF[2 * tap + 1][px];
            float m  = OFF[18 + tap][px];
            float ys = (float)(ho + tap / 3 - 1) + dy;
            float xs = (float)(px + tap % 3 - 1) + dx;
            float y0f = floorf(ys), x0f = floorf(xs);
            float fy = ys - y0f, fx = xs - x0f;
            int y0 = (int)y0f, x0 = (int)x0f;
            bool vy0 = (unsigned)y0 < 64u, vy1 = (unsigned)(y0 + 1) < 64u;
            bool vx0 = (unsigned)x0 < 64u, vx1 = (unsigned)(x0 + 1) < 64u;
            u32 w00p = pkw((vy0 && vx0) ? (1.f - fy) * (1.f - fx) * m : 0.f);
            u32 w01p = pkw((vy0 && vx1) ? (1.f - fy) * fx * m : 0.f);
            u32 w10p = pkw((vy1 && vx0) ? fy * (1.f - fx) * m : 0.f);
            u32 w11p = pkw((vy1 && vx1) ? fy * fx * m : 0.f);
            int y0c = min(max(y0, 0), 63), y1c = min(max(y0 + 1, 0), 63);
            int x0c = min(max(x0, 0), 63), x1c = min(max(x0 + 1, 0), 63);
            u32 a0 = ((u32)y0c << 6) | (u32)x0c;
            u32 a1 = ((u32)y1c << 6) | (u32)x1c;
            u32* dst = pbase + (size_t)tap * 512 + ((px >> 3) << 6);
            *(uint4*)&dst[(px & 7) << 2] = make_uint4(w00p, w01p, w10p, w11p);
            dst[32 + (px & 7)] = a0 | (a1 << 12);
        }
    }
}

// ---------------- kernel 4: fused sample + MFMA, 2-deep pipeline ----------
__global__ __launch_bounds__(512, 3) void k_fused(const u32* __restrict__ xtu,
                                                  const uint4* __restrict__ wtv,
                                                  const u32* __restrict__ params,
                                                  const float* __restrict__ bias,
                                                  float* __restrict__ out) {
    __shared__ __align__(16) u32 S[2][64][68];    // dbuf, 34.8 KB
    __shared__ __align__(16) u32 PRM[8][3][64];   // 3-deep param strips, 6 KB
    int blk = ((blockIdx.x & 7) << 7) + (blockIdx.x >> 3);   // XCD-chunked
    int t = threadIdx.x;
    int b = blk >> 6, ho = blk & 63;
    int w = t >> 6, lane = t & 63, l15 = lane & 15, lhi = lane >> 4;
    int o0 = w << 4;
    int lane4 = lane << 2;

    f32x4 acc[4];
#pragma unroll
    for (int pb = 0; pb < 4; ++pb) acc[pb] = (f32x4){0.f, 0.f, 0.f, 0.f};

    const char* xbb = (const char*)(xtu + (size_t)b * HW_ * CU_);
    const u32* pP = params + (size_t)(((b << 6) + ho) * 9) * 512 + (w << 6) + lane;

    u32 ldA[8][4], ldB[8][4];
    u32 prNext;

#define ISSUE_G(LD, PB)                                                      \
    _Pragma("unroll") for (int j = 0; j < 8; ++j) {                          \
        u32 A = PRM[w][PB][32 + j];                                          \
        u32 a0 = (A & 0xFFFu) << 8;                                          \
        u32 a1 = ((A >> 12) & 0xFFFu) << 8;                                  \
        u32 a01 = (a0 & ~0x3FFFu) | (a1 & 0x3FFFu);                          \
        u32 a10 = (a1 & ~0x3FFFu) | (a0 & 0x3FFFu);                          \
        LD[j][0] = *(const u32*)(xbb + a0 + lane4);                          \
        LD[j][1] = *(const u32*)(xbb + a01 + lane4);                         \
        LD[j][2] = *(const u32*)(xbb + a10 + lane4);                         \
        LD[j][3] = *(const u32*)(xbb + a1 + lane4);                          \
    }

#define TAP(N, LD)                                                           \
    {                                                                        \
        U16 wf[4];                                                           \
        _Pragma("unroll") for (int ks = 0; ks < 4; ++ks)                     \
            wf[ks].u = wtv[((((N) << 2) + ks) * 8 + w) * 64 + lane];         \
        __builtin_amdgcn_sched_barrier(0);                                   \
        _Pragma("unroll") for (int j = 0; j < 8; ++j) {                      \
            uint4 ww = *(const uint4*)&PRM[w][(N) % 3][j << 2];              \
            u32 r = hfma2u(LD[j][3], ww.w, hfma2u(LD[j][2], ww.z,            \
                    hfma2u(LD[j][1], ww.y, hmul2u(LD[j][0], ww.x))));        \
            S[(N) & 1][(w << 3) + j][lane] = r;                              \
        }                                                                    \
        if ((N) < 7) PRM[w][((N) + 2) % 3][lane] = prNext;                   \
        if ((N) < 6) prNext = pP[(size_t)((N) + 3) * 512];                   \
        if ((N) < 7) { ISSUE_G(LD, ((N) + 2) % 3); }                         \
        asm volatile("s_waitcnt lgkmcnt(0)" ::: "memory");                   \
        __builtin_amdgcn_sched_barrier(0);                                   \
        __builtin_amdgcn_s_barrier();                                        \
        __builtin_amdgcn_sched_barrier(0);                                   \
        __builtin_amdgcn_s_setprio(1);                                       \
        _Pragma("unroll") for (int ks = 0; ks < 4; ++ks) {                   \
            U16 sf[4];                                                       \
            _Pragma("unroll") for (int pb = 0; pb < 4; ++pb)                 \
                sf[pb].u = *(const uint4*)&S[(N) & 1][pb * 16 + l15][(ks * 4 + lhi) << 2]; \
            _Pragma("unroll") for (int pb = 0; pb < 4; ++pb)                 \
                acc[pb] = __builtin_amdgcn_mfma_f32_16x16x32_f16(            \
                    wf[ks].h, sf[pb].h, acc[pb], 0, 0, 0);                   \
        }                                                                    \
        __builtin_amdgcn_s_setprio(0);                                       \
    }

    // --- prologue: stage params 0,1; issue G(0),G(1); prefetch params(2) ---
    PRM[w][0][lane] = pP[0];
    PRM[w][1][lane] = pP[512];
    asm volatile("s_waitcnt lgkmcnt(0)" ::: "memory");
    __builtin_amdgcn_sched_barrier(0);
    ISSUE_G(ldA, 0);
    ISSUE_G(ldB, 1);
    prNext = pP[1024];

    TAP(0, ldA)
    TAP(1, ldB)
    TAP(2, ldA)
    TAP(3, ldB)
    TAP(4, ldA)
    TAP(5, ldB)
    TAP(6, ldA)
    TAP(7, ldB)
    TAP(8, ldA)

#undef ISSUE_G
#undef TAP
    // --- epilogue: o = o0+lhi*4+r, px = pb*16+l15 ---
    float* ob_base = out + (size_t)b * 128 * HW_ + ho * 64;
#pragma unroll
    for (int r = 0; r < 4; ++r) {
        int o = o0 + lhi * 4 + r;
        float bv = bias[o];
#pragma unroll
        for (int pb = 0; pb < 4; ++pb)
            ob_base[(size_t)o * HW_ + pb * 16 + l15] = acc[pb][r] + bv;
    }
}

extern "C" void kernel_launch(void* const* d_in, const int* in_sizes, int n_in,
                              void* d_out, int out_size, void* d_ws, size_t ws_size,
                              hipStream_t stream) {
    const float* x      = (const float*)d_in[0];
    const float* weight = (const float*)d_in[1];
    const float* bias   = (const float*)d_in[2];
    const float* off_w  = (const float*)d_in[3];
    const float* off_b  = (const float*)d_in[4];
    float* out = (float*)d_out;

    // ws (u32 units): xtu 4194304 | wtv 73728 (uint4) | woffu 18432 | params 4718592
    u32*   xtu    = (u32*)d_ws;
    uint4* wtv    = (uint4*)(xtu + (size_t)B_ * HW_ * CU_);
    u32*   woffu  = (u32*)wtv + 294912;
    u32*   params = woffu + 18432;

    hipLaunchKernelGGL(k_transpose, dim3(2048), dim3(256), 0, stream, x, xtu);
    hipLaunchKernelGGL(k_prep, dim3(144), dim3(256), 0, stream, weight, off_w, wtv, woffu);
    hipLaunchKernelGGL(k_offconv, dim3(1024), dim3(256), 0, stream, xtu, woffu, off_b, params);
    hipLaunchKernelGGL(k_fused, dim3(1024), dim3(512), 0, stream, xtu, wtv, params, bias, out);
}

// Round 17
// 89.881 us; speedup vs baseline: 1.1527x; 1.1527x over previous
//
#include <hip/hip_runtime.h>
#include <hip/hip_fp16.h>

// DCNv2 R17: k_fused = R15 (validated 62us) + setprio(T5) on MFMA cluster.
//   k_offconv: 2 output rows per block (512 blocks x 512 thr, 8 waves):
//   stage 4 x-rows once (2x redundancy vs 3x), wave = (row g, ob, pb0),
//   params epilogue 1152 items over 512 thr. Same validated math throughout.

typedef unsigned int u32;
typedef __attribute__((ext_vector_type(8))) _Float16 f16x8;
typedef __attribute__((ext_vector_type(4))) float f32x4;

union U16 { uint4 u; f16x8 h; };
union H2U { __half2 h2; u32 u; };

static __device__ __forceinline__ u32 pkh(float a, float b) {
    H2U c; c.h2 = __float22half2_rn(make_float2(a, b)); return c.u;
}
static __device__ __forceinline__ u32 pkw(float w) {
    __half h = __float2half_rn(w);
    H2U c; c.h2 = __half2(h, h); return c.u;
}
static __device__ __forceinline__ u32 hfma2u(u32 a, u32 w, u32 acc) {
    H2U x, y, z; x.u = a; y.u = w; z.u = acc;
    z.h2 = __hfma2(x.h2, y.h2, z.h2); return z.u;
}
static __device__ __forceinline__ u32 hmul2u(u32 a, u32 w) {
    H2U x, y; x.u = a; y.u = w;
    y.h2 = __hmul2(x.h2, y.h2); return y.u;
}

#define B_   16
#define HW_  4096
#define CU_  64          // 128 ch = 64 fp16-pair words

// ---------------- kernel 1: NCHW f32 -> NHWC fp16 ----------------
__global__ __launch_bounds__(256) void k_transpose(const float* __restrict__ x,
                                                   u32* __restrict__ xtu) {
    __shared__ float tile[32][129];
    int blk = blockIdx.x, t = threadIdx.x;
    int b = blk >> 7, hw0 = (blk & 127) << 5;
    int hwl = t & 31, cg = t >> 5;
    const float* src = x + (size_t)b * 128 * HW_ + hw0 + hwl;
#pragma unroll
    for (int i = 0; i < 16; ++i) { int c = cg + (i << 3); tile[hwl][c] = src[(size_t)c * HW_]; }
    __syncthreads();
    u32* dst = xtu + ((size_t)b * HW_ + hw0) * CU_;
    int u = t & 63, hq = t >> 6;
#pragma unroll
    for (int j = 0; j < 8; ++j) {
        int hw = (hq << 3) + j;
        dst[(size_t)hw * CU_ + u] = pkh(tile[hw][2 * u], tile[hw][2 * u + 1]);
    }
}

// ---------------- kernel 2: weight prep ----------------
__global__ __launch_bounds__(256) void k_prep(const float* __restrict__ weight,
                                              const float* __restrict__ off_w,
                                              uint4* __restrict__ wtv,
                                              u32* __restrict__ woffu) {
    int idx = blockIdx.x * 256 + threadIdx.x;
    if (idx < 18432) {
        int l = idx & 63, og = (idx >> 6) & 7, ks = (idx >> 9) & 3, n = idx >> 11;
        int o = og * 16 + (l & 15);
        int c0 = ks * 32 + (l >> 4) * 8;
        u32 r[4];
#pragma unroll
        for (int q = 0; q < 4; ++q) {
            int c = c0 + 2 * q;
            r[q] = pkh(weight[((size_t)(o * 128 + c)) * 9 + n],
                       weight[((size_t)(o * 128 + c + 1)) * 9 + n]);
        }
        wtv[idx] = make_uint4(r[0], r[1], r[2], r[3]);
    } else {
        int k = idx - 18432;
        int o = k / 576, r = k % 576;
        int tap = r / 64, cu = r % 64, c = cu * 2;
        u32 v = 0u;
        if (o < 27) {
            float a = off_w[((size_t)(o * 128 + c)) * 9 + tap];
            float b = off_w[((size_t)(o * 128 + c + 1)) * 9 + tap];
            v = pkh(a, b);
        }
        woffu[k] = v;
    }
}

// ---------------- kernel 3: offset/mask conv + params, 2 rows/block ----------
__global__ __launch_bounds__(512) void k_offconv(const u32* __restrict__ xtu,
                                                 const u32* __restrict__ woffu,
                                                 const float* __restrict__ off_b,
                                                 u32* __restrict__ params) {
    __shared__ __align__(16) u32 S4[4][64][64];   // rows ho0-1..ho0+2, 64 KB
    __shared__ float OFF[2][27][65];              // 14.1 KB
    int raw = blockIdx.x;
    int blk = ((raw & 7) << 6) + (raw >> 3);      // XCD-chunked, 512 = 8*64
    int t = threadIdx.x;
    int b = blk >> 5, rp = blk & 31, ho0 = rp << 1;
    const u32* xb = xtu + (size_t)b * HW_ * CU_;
    // --- stage 4 rows (4096 uint4, 8 per thread), clamped ---
#pragma unroll
    for (int i = 0; i < 8; ++i) {
        int idx = t + (i << 9);
        int r = idx >> 10, rem = idx & 1023;
        int px = rem >> 4, ch = rem & 15;
        int phys = min(max(ho0 - 1 + r, 0), 63);
        uint4 v = *(const uint4*)(xb + ((phys << 6) + px) * CU_ + (ch << 2));
        *(uint4*)&S4[r][px][(ch ^ (px & 7)) << 2] = v;
    }
    __syncthreads();
    int lane = t & 63, w = t >> 6, l15 = lane & 15, lhi = lane >> 4;
    int g = w >> 2, ob = (w >> 1) & 1, pb0 = (w & 1) << 1;
    const uint4 z4 = {0u, 0u, 0u, 0u};
    f32x4 acc[2];
    acc[0] = (f32x4){0.f, 0.f, 0.f, 0.f};
    acc[1] = (f32x4){0.f, 0.f, 0.f, 0.f};
#pragma unroll 1
    for (int tap = 0; tap < 9; ++tap) {
        int ky = tap / 3, kx = tap % 3;
        int yy = ho0 + g + ky - 1;
        if ((unsigned)yy >= 64u) continue;
        int br = g + ky;                          // band row 0..3
        U16 af[4];
#pragma unroll
        for (int ks = 0; ks < 4; ++ks)
            af[ks].u = *(const uint4*)(woffu + (size_t)(ob * 16 + l15) * 576
                                       + tap * 64 + ks * 16 + lhi * 4);
#pragma unroll
        for (int pp = 0; pp < 2; ++pp) {
            int pr = ((pb0 + pp) << 4) + l15;
            int pxs = pr + kx - 1;
            bool v = (unsigned)pxs < 64u;
            int pxc = v ? pxs : 0;
#pragma unroll
            for (int ks = 0; ks < 4; ++ks) {
                U16 sf;
                sf.u = v ? *(const uint4*)&S4[br][pxc][((ks * 4 + lhi) ^ (pxc & 7)) << 2] : z4;
                acc[pp] = __builtin_amdgcn_mfma_f32_16x16x32_f16(af[ks].h, sf.h, acc[pp], 0, 0, 0);
            }
        }
    }
    // --- epilogue A: offsets/mask -> OFF[g] ---
#pragma unroll
    for (int pp = 0; pp < 2; ++pp)
#pragma unroll
        for (int r = 0; r < 4; ++r) {
            int o = ob * 16 + lhi * 4 + r;
            if (o < 27) {
                float s = acc[pp][r] + off_b[o];
                if (o >= 18) s = 1.f / (1.f + __expf(-s));
                OFF[g][o][((pb0 + pp) << 4) + l15] = s;
            }
        }
    __syncthreads();
    // --- epilogue B: params for rows ho0, ho0+1: 1152 items ---
#pragma unroll 1
    for (int it = 0; it < 3; ++it) {
        int item = it * 512 + t;
        if (item < 1152) {
            int g2 = item >= 576;
            int rem = item - 576 * g2;
            int tap = rem >> 6, px = rem & 63;
            int ho = ho0 + g2;
            float dy = OFF[g2][2 * tap][px];
            float dx = OFF[g2][2 * tap + 1][px];
            float m  = OFF[g2][18 + tap][px];
            float ys = (float)(ho + tap / 3 - 1) + dy;
            float xs = (float)(px + tap % 3 - 1) + dx;
            float y0f = floorf(ys), x0f = floorf(xs);
            float fy = ys - y0f, fx = xs - x0f;
            int y0 = (int)y0f, x0 = (int)x0f;
            bool vy0 = (unsigned)y0 < 64u, vy1 = (unsigned)(y0 + 1) < 64u;
            bool vx0 = (unsigned)x0 < 64u, vx1 = (unsigned)(x0 + 1) < 64u;
            u32 w00p = pkw((vy0 && vx0) ? (1.f - fy) * (1.f - fx) * m : 0.f);
            u32 w01p = pkw((vy0 && vx1) ? (1.f - fy) * fx * m : 0.f);
            u32 w10p = pkw((vy1 && vx0) ? fy * (1.f - fx) * m : 0.f);
            u32 w11p = pkw((vy1 && vx1) ? fy * fx * m : 0.f);
            int y0c = min(max(y0, 0), 63), y1c = min(max(y0 + 1, 0), 63);
            int x0c = min(max(x0, 0), 63), x1c = min(max(x0 + 1, 0), 63);
            u32 a0 = ((u32)y0c << 6) | (u32)x0c;
            u32 a1 = ((u32)y1c << 6) | (u32)x1c;
            u32* dst = params + ((size_t)((b << 6) + ho) * 9 + tap) * 512 + ((px >> 3) << 6);
            *(uint4*)&dst[(px & 7) << 2] = make_uint4(w00p, w01p, w10p, w11p);
            dst[32 + (px & 7)] = a0 | (a1 << 12);
        }
    }
}

// ---------------- kernel 4: fused sample + MFMA (R15 + setprio) ----------
__global__ __launch_bounds__(512, 4) void k_fused(const u32* __restrict__ xtu,
                                                  const uint4* __restrict__ wtv,
                                                  const u32* __restrict__ params,
                                                  const float* __restrict__ bias,
                                                  float* __restrict__ out) {
    __shared__ __align__(16) u32 S[2][64][68];    // dbuf, 34.8 KB
    __shared__ __align__(16) u32 PRM[8][2][64];   // wave-private param strips, 4 KB
    int blk = ((blockIdx.x & 7) << 7) + (blockIdx.x >> 3);   // XCD-chunked
    int t = threadIdx.x;
    int b = blk >> 6, ho = blk & 63;
    int w = t >> 6, lane = t & 63, l15 = lane & 15, lhi = lane >> 4;
    int o0 = w << 4;
    int lane4 = lane << 2;

    f32x4 acc[4];
#pragma unroll
    for (int pb = 0; pb < 4; ++pb) acc[pb] = (f32x4){0.f, 0.f, 0.f, 0.f};

    const char* xbb = (const char*)(xtu + (size_t)b * HW_ * CU_);
    const u32* pP = params + (size_t)(((b << 6) + ho) * 9) * 512 + (w << 6) + lane;

    u32 ld[8][4];

#define ISSUE_G(NB)                                                          \
    _Pragma("unroll") for (int j = 0; j < 8; ++j) {                          \
        u32 A = PRM[w][NB][32 + j];                                          \
        u32 a0 = (A & 0xFFFu) << 8;                                          \
        u32 a1 = ((A >> 12) & 0xFFFu) << 8;                                  \
        u32 a01 = (a0 & ~0x3FFFu) | (a1 & 0x3FFFu);                          \
        u32 a10 = (a1 & ~0x3FFFu) | (a0 & 0x3FFFu);                          \
        ld[j][0] = *(const u32*)(xbb + a0 + lane4);                          \
        ld[j][1] = *(const u32*)(xbb + a01 + lane4);                         \
        ld[j][2] = *(const u32*)(xbb + a10 + lane4);                         \
        ld[j][3] = *(const u32*)(xbb + a1 + lane4);                          \
    }

    // --- prologue: stage params(0); issue G(0); prefetch params(1) ---
    PRM[w][0][lane] = pP[0];
    __builtin_amdgcn_sched_barrier(0);
    ISSUE_G(0);
    u32 prNext = pP[512];

#pragma unroll 1
    for (int n = 0; n < 9; ++n) {
        int buf = n & 1;
        // --- W(n) fragments FIRST (in-order vmcnt: MFMA's wait won't drain G) ---
        U16 wf[4];
#pragma unroll
        for (int ks = 0; ks < 4; ++ks)
            wf[ks].u = wtv[(((n << 2) + ks) * 8 + w) * 64 + lane];
        __builtin_amdgcn_sched_barrier(0);
        // --- blend(n): pre-expanded weights straight from PRM ---
#pragma unroll
        for (int j = 0; j < 8; ++j) {
            uint4 ww = *(const uint4*)&PRM[w][buf][j << 2];
            u32 r = hfma2u(ld[j][3], ww.w, hfma2u(ld[j][2], ww.z,
                    hfma2u(ld[j][1], ww.y, hmul2u(ld[j][0], ww.x))));
            S[buf][(w << 3) + j][lane] = r;
        }
        // --- stage params(n+1); prefetch params(n+2) ---
        if (n < 8) PRM[w][buf ^ 1][lane] = prNext;
        if (n < 7) prNext = pP[(size_t)(n + 2) * 512];
        // --- issue G(n+1): stays in flight across the barrier ---
        if (n < 8) { ISSUE_G(buf ^ 1); }
        // --- raw barrier: LDS drained, vmem NOT drained ---
        asm volatile("s_waitcnt lgkmcnt(0)" ::: "memory");
        __builtin_amdgcn_sched_barrier(0);
        __builtin_amdgcn_s_barrier();
        __builtin_amdgcn_sched_barrier(0);
        // --- MFMA(n): D[o0..o0+16][px] += W_tap * S_tap^T ---
        __builtin_amdgcn_s_setprio(1);
#pragma unroll
        for (int ks = 0; ks < 4; ++ks) {
            U16 sf[4];
#pragma unroll
            for (int pb = 0; pb < 4; ++pb)
                sf[pb].u = *(const uint4*)&S[buf][pb * 16 + l15][(ks * 4 + lhi) << 2];
#pragma unroll
            for (int pb = 0; pb < 4; ++pb)
                acc[pb] = __builtin_amdgcn_mfma_f32_16x16x32_f16(
                    wf[ks].h, sf[pb].h, acc[pb], 0, 0, 0);
        }
        __builtin_amdgcn_s_setprio(0);
    }
#undef ISSUE_G
    // --- epilogue: o = o0+lhi*4+r, px = pb*16+l15 ---
    float* ob_base = out + (size_t)b * 128 * HW_ + ho * 64;
#pragma unroll
    for (int r = 0; r < 4; ++r) {
        int o = o0 + lhi * 4 + r;
        float bv = bias[o];
#pragma unroll
        for (int pb = 0; pb < 4; ++pb)
            ob_base[(size_t)o * HW_ + pb * 16 + l15] = acc[pb][r] + bv;
    }
}

extern "C" void kernel_launch(void* const* d_in, const int* in_sizes, int n_in,
                              void* d_out, int out_size, void* d_ws, size_t ws_size,
                              hipStream_t stream) {
    const float* x      = (const float*)d_in[0];
    const float* weight = (const float*)d_in[1];
    const float* bias   = (const float*)d_in[2];
    const float* off_w  = (const float*)d_in[3];
    const float* off_b  = (const float*)d_in[4];
    float* out = (float*)d_out;

    // ws (u32 units): xtu 4194304 | wtv 73728 (uint4) | woffu 18432 | params 4718592
    u32*   xtu    = (u32*)d_ws;
    uint4* wtv    = (uint4*)(xtu + (size_t)B_ * HW_ * CU_);
    u32*   woffu  = (u32*)wtv + 294912;
    u32*   params = woffu + 18432;

    hipLaunchKernelGGL(k_transpose, dim3(2048), dim3(256), 0, stream, x, xtu);
    hipLaunchKernelGGL(k_prep, dim3(144), dim3(256), 0, stream, weight, off_w, wtv, woffu);
    hipLaunchKernelGGL(k_offconv, dim3(512), dim3(512), 0, stream, xtu, woffu, off_b, params);
    hipLaunchKernelGGL(k_fused, dim3(1024), dim3(512), 0, stream, xtu, wtv, params, bias, out);
}

// Round 18
// 87.419 us; speedup vs baseline: 1.1852x; 1.0282x over previous
//
#include <hip/hip_runtime.h>
#include <hip/hip_fp16.h>

// DCNv2 R18: consolidation. k_fused/k_offconv = R17 (validated 63.5us / fused-params).
//   k_transprep: transpose (2048 blocks) + weight prep (144 blocks) in ONE launch;
//   transpose phase-2 reads channel pairs via ds_read_b64 (tile padded to [32][130]).

typedef unsigned int u32;
typedef __attribute__((ext_vector_type(8))) _Float16 f16x8;
typedef __attribute__((ext_vector_type(4))) float f32x4;

union U16 { uint4 u; f16x8 h; };
union H2U { __half2 h2; u32 u; };

static __device__ __forceinline__ u32 pkh(float a, float b) {
    H2U c; c.h2 = __float22half2_rn(make_float2(a, b)); return c.u;
}
static __device__ __forceinline__ u32 pkw(float w) {
    __half h = __float2half_rn(w);
    H2U c; c.h2 = __half2(h, h); return c.u;
}
static __device__ __forceinline__ u32 hfma2u(u32 a, u32 w, u32 acc) {
    H2U x, y, z; x.u = a; y.u = w; z.u = acc;
    z.h2 = __hfma2(x.h2, y.h2, z.h2); return z.u;
}
static __device__ __forceinline__ u32 hmul2u(u32 a, u32 w) {
    H2U x, y; x.u = a; y.u = w;
    y.h2 = __hmul2(x.h2, y.h2); return y.u;
}

#define B_   16
#define HW_  4096
#define CU_  64          // 128 ch = 64 fp16-pair words

// ---------------- kernel 1: transpose + weight prep (merged) ----------------
__global__ __launch_bounds__(256) void k_transprep(const float* __restrict__ x,
                                                   u32* __restrict__ xtu,
                                                   const float* __restrict__ weight,
                                                   const float* __restrict__ off_w,
                                                   uint4* __restrict__ wtv,
                                                   u32* __restrict__ woffu) {
    int blk = blockIdx.x, t = threadIdx.x;
    if (blk < 2048) {
        // --- NCHW f32 -> NHWC fp16 ---
        __shared__ float tile[32][130];
        int b = blk >> 7, hw0 = (blk & 127) << 5;
        int hwl = t & 31, cg = t >> 5;
        const float* src = x + (size_t)b * 128 * HW_ + hw0 + hwl;
#pragma unroll
        for (int i = 0; i < 16; ++i) { int c = cg + (i << 3); tile[hwl][c] = src[(size_t)c * HW_]; }
        __syncthreads();
        u32* dst = xtu + ((size_t)b * HW_ + hw0) * CU_;
        int u = t & 63, hq = t >> 6;
#pragma unroll
        for (int j = 0; j < 8; ++j) {
            int hw = (hq << 3) + j;
            float2 rd = *(const float2*)&tile[hw][2 * u];    // ds_read_b64
            dst[(size_t)hw * CU_ + u] = pkh(rd.x, rd.y);
        }
    } else {
        // --- weight prep ---
        int idx = (blk - 2048) * 256 + t;
        if (idx < 18432) {
            int l = idx & 63, og = (idx >> 6) & 7, ks = (idx >> 9) & 3, n = idx >> 11;
            int o = og * 16 + (l & 15);
            int c0 = ks * 32 + (l >> 4) * 8;
            u32 r[4];
#pragma unroll
            for (int q = 0; q < 4; ++q) {
                int c = c0 + 2 * q;
                r[q] = pkh(weight[((size_t)(o * 128 + c)) * 9 + n],
                           weight[((size_t)(o * 128 + c + 1)) * 9 + n]);
            }
            wtv[idx] = make_uint4(r[0], r[1], r[2], r[3]);
        } else if (idx < 36864) {
            int k = idx - 18432;
            int o = k / 576, r = k % 576;
            int tap = r / 64, cu = r % 64, c = cu * 2;
            u32 v = 0u;
            if (o < 27) {
                float a = off_w[((size_t)(o * 128 + c)) * 9 + tap];
                float b = off_w[((size_t)(o * 128 + c + 1)) * 9 + tap];
                v = pkh(a, b);
            }
            woffu[k] = v;
        }
    }
}

// ---------------- kernel 3: offset/mask conv + params, 2 rows/block ----------
__global__ __launch_bounds__(512) void k_offconv(const u32* __restrict__ xtu,
                                                 const u32* __restrict__ woffu,
                                                 const float* __restrict__ off_b,
                                                 u32* __restrict__ params) {
    __shared__ __align__(16) u32 S4[4][64][64];   // rows ho0-1..ho0+2, 64 KB
    __shared__ float OFF[2][27][65];              // 14.1 KB
    int raw = blockIdx.x;
    int blk = ((raw & 7) << 6) + (raw >> 3);      // XCD-chunked, 512 = 8*64
    int t = threadIdx.x;
    int b = blk >> 5, rp = blk & 31, ho0 = rp << 1;
    const u32* xb = xtu + (size_t)b * HW_ * CU_;
    // --- stage 4 rows (4096 uint4, 8 per thread), clamped ---
#pragma unroll
    for (int i = 0; i < 8; ++i) {
        int idx = t + (i << 9);
        int r = idx >> 10, rem = idx & 1023;
        int px = rem >> 4, ch = rem & 15;
        int phys = min(max(ho0 - 1 + r, 0), 63);
        uint4 v = *(const uint4*)(xb + ((phys << 6) + px) * CU_ + (ch << 2));
        *(uint4*)&S4[r][px][(ch ^ (px & 7)) << 2] = v;
    }
    __syncthreads();
    int lane = t & 63, w = t >> 6, l15 = lane & 15, lhi = lane >> 4;
    int g = w >> 2, ob = (w >> 1) & 1, pb0 = (w & 1) << 1;
    const uint4 z4 = {0u, 0u, 0u, 0u};
    f32x4 acc[2];
    acc[0] = (f32x4){0.f, 0.f, 0.f, 0.f};
    acc[1] = (f32x4){0.f, 0.f, 0.f, 0.f};
#pragma unroll 1
    for (int tap = 0; tap < 9; ++tap) {
        int ky = tap / 3, kx = tap % 3;
        int yy = ho0 + g + ky - 1;
        if ((unsigned)yy >= 64u) continue;
        int br = g + ky;                          // band row 0..3
        U16 af[4];
#pragma unroll
        for (int ks = 0; ks < 4; ++ks)
            af[ks].u = *(const uint4*)(woffu + (size_t)(ob * 16 + l15) * 576
                                       + tap * 64 + ks * 16 + lhi * 4);
#pragma unroll
        for (int pp = 0; pp < 2; ++pp) {
            int pr = ((pb0 + pp) << 4) + l15;
            int pxs = pr + kx - 1;
            bool v = (unsigned)pxs < 64u;
            int pxc = v ? pxs : 0;
#pragma unroll
            for (int ks = 0; ks < 4; ++ks) {
                U16 sf;
                sf.u = v ? *(const uint4*)&S4[br][pxc][((ks * 4 + lhi) ^ (pxc & 7)) << 2] : z4;
                acc[pp] = __builtin_amdgcn_mfma_f32_16x16x32_f16(af[ks].h, sf.h, acc[pp], 0, 0, 0);
            }
        }
    }
    // --- epilogue A: offsets/mask -> OFF[g] ---
#pragma unroll
    for (int pp = 0; pp < 2; ++pp)
#pragma unroll
        for (int r = 0; r < 4; ++r) {
            int o = ob * 16 + lhi * 4 + r;
            if (o < 27) {
                float s = acc[pp][r] + off_b[o];
                if (o >= 18) s = 1.f / (1.f + __expf(-s));
                OFF[g][o][((pb0 + pp) << 4) + l15] = s;
            }
        }
    __syncthreads();
    // --- epilogue B: params for rows ho0, ho0+1: 1152 items ---
#pragma unroll 1
    for (int it = 0; it < 3; ++it) {
        int item = it * 512 + t;
        if (item < 1152) {
            int g2 = item >= 576;
            int rem = item - 576 * g2;
            int tap = rem >> 6, px = rem & 63;
            int ho = ho0 + g2;
            float dy = OFF[g2][2 * tap][px];
            float dx = OFF[g2][2 * tap + 1][px];
            float m  = OFF[g2][18 + tap][px];
            float ys = (float)(ho + tap / 3 - 1) + dy;
            float xs = (float)(px + tap % 3 - 1) + dx;
            float y0f = floorf(ys), x0f = floorf(xs);
            float fy = ys - y0f, fx = xs - x0f;
            int y0 = (int)y0f, x0 = (int)x0f;
            bool vy0 = (unsigned)y0 < 64u, vy1 = (unsigned)(y0 + 1) < 64u;
            bool vx0 = (unsigned)x0 < 64u, vx1 = (unsigned)(x0 + 1) < 64u;
            u32 w00p = pkw((vy0 && vx0) ? (1.f - fy) * (1.f - fx) * m : 0.f);
            u32 w01p = pkw((vy0 && vx1) ? (1.f - fy) * fx * m : 0.f);
            u32 w10p = pkw((vy1 && vx0) ? fy * (1.f - fx) * m : 0.f);
            u32 w11p = pkw((vy1 && vx1) ? fy * fx * m : 0.f);
            int y0c = min(max(y0, 0), 63), y1c = min(max(y0 + 1, 0), 63);
            int x0c = min(max(x0, 0), 63), x1c = min(max(x0 + 1, 0), 63);
            u32 a0 = ((u32)y0c << 6) | (u32)x0c;
            u32 a1 = ((u32)y1c << 6) | (u32)x1c;
            u32* dst = params + ((size_t)((b << 6) + ho) * 9 + tap) * 512 + ((px >> 3) << 6);
            *(uint4*)&dst[(px & 7) << 2] = make_uint4(w00p, w01p, w10p, w11p);
            dst[32 + (px & 7)] = a0 | (a1 << 12);
        }
    }
}

// ---------------- kernel 4: fused sample + MFMA (R17, validated) ----------
__global__ __launch_bounds__(512, 4) void k_fused(const u32* __restrict__ xtu,
                                                  const uint4* __restrict__ wtv,
                                                  const u32* __restrict__ params,
                                                  const float* __restrict__ bias,
                                                  float* __restrict__ out) {
    __shared__ __align__(16) u32 S[2][64][68];    // dbuf, 34.8 KB
    __shared__ __align__(16) u32 PRM[8][2][64];   // wave-private param strips, 4 KB
    int blk = ((blockIdx.x & 7) << 7) + (blockIdx.x >> 3);   // XCD-chunked
    int t = threadIdx.x;
    int b = blk >> 6, ho = blk & 63;
    int w = t >> 6, lane = t & 63, l15 = lane & 15, lhi = lane >> 4;
    int o0 = w << 4;
    int lane4 = lane << 2;

    f32x4 acc[4];
#pragma unroll
    for (int pb = 0; pb < 4; ++pb) acc[pb] = (f32x4){0.f, 0.f, 0.f, 0.f};

    const char* xbb = (const char*)(xtu + (size_t)b * HW_ * CU_);
    const u32* pP = params + (size_t)(((b << 6) + ho) * 9) * 512 + (w << 6) + lane;

    u32 ld[8][4];

#define ISSUE_G(NB)                                                          \
    _Pragma("unroll") for (int j = 0; j < 8; ++j) {                          \
        u32 A = PRM[w][NB][32 + j];                                          \
        u32 a0 = (A & 0xFFFu) << 8;                                          \
        u32 a1 = ((A >> 12) & 0xFFFu) << 8;                                  \
        u32 a01 = (a0 & ~0x3FFFu) | (a1 & 0x3FFFu);                          \
        u32 a10 = (a1 & ~0x3FFFu) | (a0 & 0x3FFFu);                          \
        ld[j][0] = *(const u32*)(xbb + a0 + lane4);                          \
        ld[j][1] = *(const u32*)(xbb + a01 + lane4);                         \
        ld[j][2] = *(const u32*)(xbb + a10 + lane4);                         \
        ld[j][3] = *(const u32*)(xbb + a1 + lane4);                          \
    }

    // --- prologue: stage params(0); issue G(0); prefetch params(1) ---
    PRM[w][0][lane] = pP[0];
    __builtin_amdgcn_sched_barrier(0);
    ISSUE_G(0);
    u32 prNext = pP[512];

#pragma unroll 1
    for (int n = 0; n < 9; ++n) {
        int buf = n & 1;
        // --- W(n) fragments FIRST (in-order vmcnt: MFMA's wait won't drain G) ---
        U16 wf[4];
#pragma unroll
        for (int ks = 0; ks < 4; ++ks)
            wf[ks].u = wtv[(((n << 2) + ks) * 8 + w) * 64 + lane];
        __builtin_amdgcn_sched_barrier(0);
        // --- blend(n): pre-expanded weights straight from PRM ---
#pragma unroll
        for (int j = 0; j < 8; ++j) {
            uint4 ww = *(const uint4*)&PRM[w][buf][j << 2];
            u32 r = hfma2u(ld[j][3], ww.w, hfma2u(ld[j][2], ww.z,
                    hfma2u(ld[j][1], ww.y, hmul2u(ld[j][0], ww.x))));
            S[buf][(w << 3) + j][lane] = r;
        }
        // --- stage params(n+1); prefetch params(n+2) ---
        if (n < 8) PRM[w][buf ^ 1][lane] = prNext;
        if (n < 7) prNext = pP[(size_t)(n + 2) * 512];
        // --- issue G(n+1): stays in flight across the barrier ---
        if (n < 8) { ISSUE_G(buf ^ 1); }
        // --- raw barrier: LDS drained, vmem NOT drained ---
        asm volatile("s_waitcnt lgkmcnt(0)" ::: "memory");
        __builtin_amdgcn_sched_barrier(0);
        __builtin_amdgcn_s_barrier();
        __builtin_amdgcn_sched_barrier(0);
        // --- MFMA(n): D[o0..o0+16][px] += W_tap * S_tap^T ---
        __builtin_amdgcn_s_setprio(1);
#pragma unroll
        for (int ks = 0; ks < 4; ++ks) {
            U16 sf[4];
#pragma unroll
            for (int pb = 0; pb < 4; ++pb)
                sf[pb].u = *(const uint4*)&S[buf][pb * 16 + l15][(ks * 4 + lhi) << 2];
#pragma unroll
            for (int pb = 0; pb < 4; ++pb)
                acc[pb] = __builtin_amdgcn_mfma_f32_16x16x32_f16(
                    wf[ks].h, sf[pb].h, acc[pb], 0, 0, 0);
        }
        __builtin_amdgcn_s_setprio(0);
    }
#undef ISSUE_G
    // --- epilogue: o = o0+lhi*4+r, px = pb*16+l15 ---
    float* ob_base = out + (size_t)b * 128 * HW_ + ho * 64;
#pragma unroll
    for (int r = 0; r < 4; ++r) {
        int o = o0 + lhi * 4 + r;
        float bv = bias[o];
#pragma unroll
        for (int pb = 0; pb < 4; ++pb)
            ob_base[(size_t)o * HW_ + pb * 16 + l15] = acc[pb][r] + bv;
    }
}

extern "C" void kernel_launch(void* const* d_in, const int* in_sizes, int n_in,
                              void* d_out, int out_size, void* d_ws, size_t ws_size,
                              hipStream_t stream) {
    const float* x      = (const float*)d_in[0];
    const float* weight = (const float*)d_in[1];
    const float* bias   = (const float*)d_in[2];
    const float* off_w  = (const float*)d_in[3];
    const float* off_b  = (const float*)d_in[4];
    float* out = (float*)d_out;

    // ws (u32 units): xtu 4194304 | wtv 73728 (uint4) | woffu 18432 | params 4718592
    u32*   xtu    = (u32*)d_ws;
    uint4* wtv    = (uint4*)(xtu + (size_t)B_ * HW_ * CU_);
    u32*   woffu  = (u32*)wtv + 294912;
    u32*   params = woffu + 18432;

    hipLaunchKernelGGL(k_transprep, dim3(2048 + 144), dim3(256), 0, stream,
                       x, xtu, weight, off_w, wtv, woffu);
    hipLaunchKernelGGL(k_offconv, dim3(512), dim3(512), 0, stream, xtu, woffu, off_b, params);
    hipLaunchKernelGGL(k_fused, dim3(1024), dim3(512), 0, stream, xtu, wtv, params, bias, out);
}